// Round 4
// baseline (197.168 us; speedup 1.0000x reference)
//
#include <hip/hip_runtime.h>
#include <hip/hip_bf16.h>

#define BT 262144
#define BLOCK 256
#define ROWS_PER_BLOCK 128

typedef __attribute__((ext_vector_type(8))) short short8;
typedef __attribute__((ext_vector_type(16))) float f32x16;

__device__ __forceinline__ unsigned short f2bf(float f) {
  union { __hip_bfloat16 b; unsigned short u; } v;
  v.b = __float2bfloat16(f);
  return v.u;
}
__device__ __forceinline__ float frcp(float x) { return __builtin_amdgcn_rcpf(x); }
__device__ __forceinline__ float sigm(float x) { return frcp(1.0f + __expf(-x)); }
__device__ __forceinline__ float tanh_(float x) {
  float e = __expf(-2.0f * x);
  return (1.0f - e) * frcp(1.0f + e);
}

// Prep for 32x32x16 MFMA tiles.
// Gate B-fragments (ids 0..32767):
//   id = ((((cp*4 + ks)*8 + fo)*64 + l)*8 + j,  fo = op*4 + gt
//   value = W[n][k],  n = gt*64 + cp*32 + (l&31),  k = ks*16 + (l>>5)*8 + j
//   op0 = W_eff = W_ih@W_in (obs operand), op1 = W_hh (h operand)
// Each (cp,ks) group is a contiguous 4 KB block -> streaming L1 reads.
// W_out fragments (ids 32768..34815): e=(id-32768): j=e&7,l=(e>>3)&63,ks=e>>9
//   n = l&31 (zero-padded for n>=16), k = ks*16 + (l>>5)*8 + j
// b_eff at ids 34816..35071.
__global__ void prep_kernel(const float* __restrict__ W_in, const float* __restrict__ b_in,
                            const float* __restrict__ W_ih, const float* __restrict__ W_hh,
                            const float* __restrict__ b_ih, const float* __restrict__ b_hh,
                            const float* __restrict__ W_out,
                            unsigned short* __restrict__ wsW, float* __restrict__ ws_beff) {
  int id = blockIdx.x * blockDim.x + threadIdx.x;
  if (id < 32768) {                       // gate fragments
    int j = id & 7, l = (id >> 3) & 63, fo = (id >> 9) & 7;
    int ks = (id >> 12) & 3, cp = (id >> 14) & 1;
    int gt = fo & 3, op = fo >> 2;
    int n = gt * 64 + cp * 32 + (l & 31);
    int k = ks * 16 + (l >> 5) * 8 + j;
    float s;
    if (op == 0) {
      s = 0.f;
      #pragma unroll 8
      for (int h = 0; h < 64; ++h) s = fmaf(W_ih[n * 64 + h], W_in[h * 64 + k], s);
    } else {
      s = W_hh[n * 64 + k];
    }
    wsW[id] = f2bf(s);
  } else if (id < 34816) {                // W_out fragments (padded to 32 cols)
    int e = id - 32768;
    int j = e & 7, l = (e >> 3) & 63, ks = e >> 9;
    int n = l & 31;
    int k = ks * 16 + (l >> 5) * 8 + j;
    wsW[id] = (n < 16) ? f2bf(W_out[n * 64 + k]) : (unsigned short)0;
  } else if (id < 35072) {                // b_eff
    int n = id - 34816;
    float s = b_ih[n] + b_hh[n];
    #pragma unroll 8
    for (int h = 0; h < 64; ++h) s = fmaf(W_ih[n * 64 + h], b_in[h], s);
    ws_beff[n] = s;
  }
}

__device__ __forceinline__ short8 pack8(float4 lo, float4 hi) {
  short8 r;
  r[0] = (short)f2bf(lo.x); r[1] = (short)f2bf(lo.y);
  r[2] = (short)f2bf(lo.z); r[3] = (short)f2bf(lo.w);
  r[4] = (short)f2bf(hi.x); r[5] = (short)f2bf(hi.y);
  r[6] = (short)f2bf(hi.z); r[7] = (short)f2bf(hi.w);
  return r;
}

// 32 rows per wave via 32x32x16 MFMA. B-fragments from global (L2-hot).
// No barriers; only LDS is the per-wave 4 KB XOR-swizzled h_new transpose buf.
__global__ __launch_bounds__(BLOCK, 3) void lstm_main(
    const float* __restrict__ obs, const float* __restrict__ h0,
    const float* __restrict__ c0, const float* __restrict__ b_out,
    const unsigned short* __restrict__ wsW, const float* __restrict__ ws_beff,
    float* __restrict__ out) {
  __shared__ __attribute__((aligned(16))) unsigned short hbuf_s[4][2048];

  const int tid = threadIdx.x;
  const int wv = tid >> 6;
  const int lane = tid & 63;
  const int l32 = lane & 31;
  const int half = lane >> 5;              // 0..1
  const size_t rowbase = (size_t)blockIdx.x * ROWS_PER_BLOCK + (size_t)wv * 32;
  const size_t row = rowbase + (size_t)l32;

  // ---- A-operand loads (obs, h0): 8 consecutive floats per ks ----
  const float* po = obs + row * 64 + half * 8;
  const float* ph = h0 + row * 64 + half * 8;
  short8 aO[4], aH[4];
  #pragma unroll
  for (int ks = 0; ks < 4; ++ks) {
    float4 lo = *(const float4*)(po + ks * 16);
    float4 hi = *(const float4*)(po + ks * 16 + 4);
    aO[ks] = pack8(lo, hi);
  }
  #pragma unroll
  for (int ks = 0; ks < 4; ++ks) {
    float4 lo = *(const float4*)(ph + ks * 16);
    float4 hi = *(const float4*)(ph + ks * 16 + 4);
    aH[ks] = pack8(lo, hi);
  }

  const short8* W = (const short8*)wsW;
  float* out_act = out;
  float* out_h = out + (size_t)BT * 16;
  float* out_c = out + (size_t)BT * 80;
  unsigned short* hb = &hbuf_s[wv][0];

  #pragma unroll
  for (int cp = 0; cp < 2; ++cp) {
    // c0 for this column pair (rows per D-layout)
    float cold[16];
    #pragma unroll
    for (int r = 0; r < 16; ++r) {
      int hrow = (r & 3) + 8 * (r >> 2) + 4 * half;
      cold[r] = c0[(rowbase + (size_t)hrow) * 64 + cp * 32 + l32];
    }
    float bi = ws_beff[0 * 64 + cp * 32 + l32];
    float bf = ws_beff[1 * 64 + cp * 32 + l32];
    float bg = ws_beff[2 * 64 + cp * 32 + l32];
    float bo = ws_beff[3 * 64 + cp * 32 + l32];
    f32x16 aI, aF, aG, aOg;
    #pragma unroll
    for (int r = 0; r < 16; ++r) { aI[r] = bi; aF[r] = bf; aG[r] = bg; aOg[r] = bo; }

    #pragma unroll
    for (int ks = 0; ks < 4; ++ks) {
      const short8* pb = W + (size_t)((cp * 4 + ks) * 8) * 64;
      aI  = __builtin_amdgcn_mfma_f32_32x32x16_bf16(aO[ks], pb[0 * 64 + lane], aI, 0, 0, 0);
      aF  = __builtin_amdgcn_mfma_f32_32x32x16_bf16(aO[ks], pb[1 * 64 + lane], aF, 0, 0, 0);
      aG  = __builtin_amdgcn_mfma_f32_32x32x16_bf16(aO[ks], pb[2 * 64 + lane], aG, 0, 0, 0);
      aOg = __builtin_amdgcn_mfma_f32_32x32x16_bf16(aO[ks], pb[3 * 64 + lane], aOg, 0, 0, 0);
      aI  = __builtin_amdgcn_mfma_f32_32x32x16_bf16(aH[ks], pb[4 * 64 + lane], aI, 0, 0, 0);
      aF  = __builtin_amdgcn_mfma_f32_32x32x16_bf16(aH[ks], pb[5 * 64 + lane], aF, 0, 0, 0);
      aG  = __builtin_amdgcn_mfma_f32_32x32x16_bf16(aH[ks], pb[6 * 64 + lane], aG, 0, 0, 0);
      aOg = __builtin_amdgcn_mfma_f32_32x32x16_bf16(aH[ks], pb[7 * 64 + lane], aOg, 0, 0, 0);
    }

    // elementwise LSTM; D layout: lane holds col cp*32+l32, row (r&3)+8(r>>2)+4*half
    #pragma unroll
    for (int r = 0; r < 16; ++r) {
      float iv = sigm(aI[r]);
      float fv = sigm(aF[r]);
      float gv = tanh_(aG[r]);
      float ov = sigm(aOg[r]);
      int hrow = (r & 3) + 8 * (r >> 2) + 4 * half;
      size_t m = rowbase + (size_t)hrow;
      int n = cp * 32 + l32;
      float cnew = fmaf(fv, cold[r], iv * gv);
      float hnew = ov * tanh_(cnew);
      out_c[m * 64 + n] = cnew;
      out_h[m * 64 + n] = hnew;
      // XOR-swizzled transpose buffer (u16 units): breaks the 128B-stride bank conflict
      hb[hrow * 64 + (n ^ ((hrow & 7) << 3))] = f2bf(hnew);
    }
  }
  // hb is per-wave: same-wave ds ordering handled by compiler waitcnts

  // ---- action = tanh(h_new @ W_out^T + b_out) ----
  float boA = b_out[l32 & 15];
  f32x16 aA;
  #pragma unroll
  for (int r = 0; r < 16; ++r) aA[r] = boA;
  #pragma unroll
  for (int ks = 0; ks < 4; ++ks) {
    short8 av = *(const short8*)(hb + l32 * 64 + ((ks * 16 + half * 8) ^ ((l32 & 7) << 3)));
    aA = __builtin_amdgcn_mfma_f32_32x32x16_bf16(av, W[4096 + ks * 64 + lane], aA, 0, 0, 0);
  }
  #pragma unroll
  for (int r = 0; r < 16; ++r) {
    if (l32 < 16) {
      size_t m = rowbase + (size_t)((r & 3) + 8 * (r >> 2) + 4 * half);
      out_act[m * 16 + l32] = tanh_(aA[r]);
    }
  }
}

extern "C" void kernel_launch(void* const* d_in, const int* in_sizes, int n_in,
                              void* d_out, int out_size, void* d_ws, size_t ws_size,
                              hipStream_t stream) {
  const float* obs  = (const float*)d_in[0];
  const float* h0   = (const float*)d_in[1];
  const float* c0   = (const float*)d_in[2];
  const float* W_in = (const float*)d_in[3];
  const float* b_in = (const float*)d_in[4];
  const float* W_ih = (const float*)d_in[5];
  const float* W_hh = (const float*)d_in[6];
  const float* b_ih = (const float*)d_in[7];
  const float* b_hh = (const float*)d_in[8];
  const float* W_out = (const float*)d_in[9];
  const float* b_out = (const float*)d_in[10];

  unsigned short* wsW = (unsigned short*)d_ws;
  float* ws_beff = (float*)((char*)d_ws + 69632);

  prep_kernel<<<137, 256, 0, stream>>>(W_in, b_in, W_ih, W_hh, b_ih, b_hh, W_out, wsW, ws_beff);
  lstm_main<<<BT / ROWS_PER_BLOCK, BLOCK, 0, stream>>>(obs, h0, c0, b_out, wsW, ws_beff, (float*)d_out);
}

// Round 5
// 114.460 us; speedup vs baseline: 1.7226x; 1.7226x over previous
//
#include <hip/hip_runtime.h>
#include <hip/hip_bf16.h>

#define BT 262144
#define TILE 128
#define BLOCK 512

typedef __attribute__((ext_vector_type(8))) short short8;
typedef __attribute__((ext_vector_type(4))) float f32x4;
typedef __attribute__((ext_vector_type(4))) unsigned short u16x4;

__device__ __forceinline__ unsigned short f2bf(float f) {
  union { __hip_bfloat16 b; unsigned short u; } v;
  v.b = __float2bfloat16(f);
  return v.u;
}
__device__ __forceinline__ float frcp(float x) { return __builtin_amdgcn_rcpf(x); }
__device__ __forceinline__ float sigm(float x) { return frcp(1.0f + __expf(-x)); }
__device__ __forceinline__ float tanh_(float x) {
  float e = __expf(-2.0f * x);
  return (1.0f - e) * frcp(1.0f + e);
}

// Prep: W_eff = W_ih @ W_in, b_eff = b_ih + b_hh + W_ih @ b_in.
// COLUMN-PERMUTED gate fragments: tile a (= gate g*4 + t) maps fragment col
// l16 -> actual gate col 4*l16 + t, so after the D-layout each lane owns 4
// CONSECUTIVE output columns -> dwordx4 c0 loads and c/h stores.
//   wE  ids [0,16384):      id = ((ks*16 + a)*64 + l)*8 + j
//       n = (a>>2)*64 + 4*(l&15) + (a&3), k = ks*32 + (l>>4)*8 + j
//   wH  ids [16384,32768):  same mapping, value = W_hh[n][k]
//   wO  ids [32768,33792):  (ks*64 + l)*8 + j, n = l&15, k = ks*32+(l>>4)*8+j
//   b_eff ids [33792,34048): floats at byte offset 67584
__global__ void prep_kernel(const float* __restrict__ W_in, const float* __restrict__ b_in,
                            const float* __restrict__ W_ih, const float* __restrict__ W_hh,
                            const float* __restrict__ b_ih, const float* __restrict__ b_hh,
                            const float* __restrict__ W_out,
                            unsigned short* __restrict__ wsW, float* __restrict__ ws_beff) {
  int id = blockIdx.x * blockDim.x + threadIdx.x;
  if (id < 16384) {                       // W_eff fragments
    int j = id & 7, l = (id >> 3) & 63, a = (id >> 9) & 15, ks = id >> 13;
    int n = (a >> 2) * 64 + 4 * (l & 15) + (a & 3);
    int k = ks * 32 + (l >> 4) * 8 + j;
    float s = 0.f;
    #pragma unroll 8
    for (int h = 0; h < 64; ++h) s = fmaf(W_ih[n * 64 + h], W_in[h * 64 + k], s);
    wsW[id] = f2bf(s);
  } else if (id < 32768) {                // W_hh fragments
    int e = id - 16384;
    int j = e & 7, l = (e >> 3) & 63, a = (e >> 9) & 15, ks = (e >> 13) & 1;
    int n = (a >> 2) * 64 + 4 * (l & 15) + (a & 3);
    int k = ks * 32 + (l >> 4) * 8 + j;
    wsW[id] = f2bf(W_hh[n * 64 + k]);
  } else if (id < 33792) {                // W_out fragments (unpermuted)
    int e = id - 32768;
    int j = e & 7, l = (e >> 3) & 63, ks = e >> 9;
    int n = l & 15;
    int k = ks * 32 + (l >> 4) * 8 + j;
    wsW[id] = f2bf(W_out[n * 64 + k]);
  } else if (id < 34048) {                // b_eff
    int n = id - 33792;
    float s = b_ih[n] + b_hh[n];
    #pragma unroll 8
    for (int h = 0; h < 64; ++h) s = fmaf(W_ih[n * 64 + h], b_in[h], s);
    ws_beff[n] = s;
  }
}

__device__ __forceinline__ short8 pack8(float4 lo, float4 hi) {
  short8 r;
  r[0] = (short)f2bf(lo.x); r[1] = (short)f2bf(lo.y);
  r[2] = (short)f2bf(lo.z); r[3] = (short)f2bf(lo.w);
  r[4] = (short)f2bf(hi.x); r[5] = (short)f2bf(hi.y);
  r[6] = (short)f2bf(hi.z); r[7] = (short)f2bf(hi.w);
  return r;
}

__global__ __launch_bounds__(BLOCK, 4) void lstm_main(
    const float* __restrict__ obs, const float* __restrict__ h0,
    const float* __restrict__ c0, const float* __restrict__ b_out,
    const unsigned short* __restrict__ wsW, const float* __restrict__ ws_beff,
    float* __restrict__ out) {
  // 68608 B staged image (weights + wO + beff); hfrag transpose buffer is
  // UNIONED into the wE region (dead after gate MFMAs, barrier in between).
  __shared__ __attribute__((aligned(16))) unsigned char sbuf[68608];
  unsigned short* sw = (unsigned short*)sbuf;

  const int tid = threadIdx.x;
  const int wv = tid >> 6;
  const int lane = tid & 63;
  const int l16 = lane & 15;
  const int q = lane >> 4;                 // 0..3
  const size_t rowbase = (size_t)blockIdx.x * TILE + (size_t)wv * 16;

  // ---- issue ALL streaming loads early (obs/h0 A-operands + c0 + b_out) ----
  const float* po = obs + (rowbase + l16) * 64 + q * 8;
  const float* ph = h0 + (rowbase + l16) * 64 + q * 8;
  float4 ro0 = *(const float4*)(po);
  float4 ro1 = *(const float4*)(po + 4);
  float4 ro2 = *(const float4*)(po + 32);
  float4 ro3 = *(const float4*)(po + 36);
  float4 rh0 = *(const float4*)(ph);
  float4 rh1 = *(const float4*)(ph + 4);
  float4 rh2 = *(const float4*)(ph + 32);
  float4 rh3 = *(const float4*)(ph + 36);
  f32x4 cold[4];
  #pragma unroll
  for (int r = 0; r < 4; ++r)
    cold[r] = *(const f32x4*)(c0 + (rowbase + (size_t)(4 * q + r)) * 64 + 4 * l16);
  float boA = b_out[l16];

  // ---- stage full image -> LDS (4288 uint4) ----
  for (int i = tid; i < 4288; i += BLOCK)
    ((uint4*)sbuf)[i] = ((const uint4*)wsW)[i];
  __syncthreads();

  short8 aObs[2], aH[2];
  aObs[0] = pack8(ro0, ro1); aObs[1] = pack8(ro2, ro3);
  aH[0]   = pack8(rh0, rh1); aH[1]   = pack8(rh2, rh3);

  const float* beff_s = (const float*)(sbuf + 67584);
  f32x4 acc[16];
  #pragma unroll
  for (int a = 0; a < 16; ++a) {
    float b = beff_s[(a >> 2) * 64 + 4 * l16 + (a & 3)];
    acc[a] = (f32x4){b, b, b, b};
  }

  const short8* wEv = (const short8*)sw;              // [2][16][64]
  const short8* wHv = (const short8*)(sw + 16384);    // [2][16][64]
  const short8* wOv = (const short8*)(sw + 32768);    // [2][64]
  #pragma unroll
  for (int ks = 0; ks < 2; ++ks) {
    #pragma unroll
    for (int a = 0; a < 16; ++a) {
      acc[a] = __builtin_amdgcn_mfma_f32_16x16x32_bf16(aObs[ks], wEv[(ks * 16 + a) * 64 + lane], acc[a], 0, 0, 0);
      acc[a] = __builtin_amdgcn_mfma_f32_16x16x32_bf16(aH[ks],  wHv[(ks * 16 + a) * 64 + lane], acc[a], 0, 0, 0);
    }
  }

  // wE region dead -> reuse as per-wave h_new transpose buffer
  __syncthreads();
  unsigned short* hb = sw + wv * 1024;    // 16 rows x 64 cols u16, XOR-swizzled

  float* out_act = out;
  float* out_h = out + (size_t)BT * 16;
  float* out_c = out + (size_t)BT * 80;

  // elementwise; D layout: lane holds row 4q+r, cols 4*l16 + t (t=0..3)
  #pragma unroll
  for (int r = 0; r < 4; ++r) {
    f32x4 c4, h4;
    u16x4 hb4;
    #pragma unroll
    for (int t = 0; t < 4; ++t) {
      float iv = sigm(acc[t][r]);
      float fv = sigm(acc[4 + t][r]);
      float gv = tanh_(acc[8 + t][r]);
      float ov = sigm(acc[12 + t][r]);
      float cnew = fmaf(fv, cold[r][t], iv * gv);
      float hnew = ov * tanh_(cnew);
      c4[t] = cnew;
      h4[t] = hnew;
      hb4[t] = f2bf(hnew);
    }
    const int hrow = 4 * q + r;
    const size_t m = rowbase + (size_t)hrow;
    *(f32x4*)(out_c + m * 64 + 4 * l16) = c4;
    *(f32x4*)(out_h + m * 64 + 4 * l16) = h4;
    *(u16x4*)(hb + hrow * 64 + ((4 * l16) ^ ((hrow & 7) << 3))) = hb4;
  }
  // hb is per-wave: same-wave ds_write -> ds_read ordering via lgkmcnt

  // ---- action = tanh(h_new @ W_out^T + b_out); [-1,1] range => identity ----
  f32x4 aA = (f32x4){boA, boA, boA, boA};
  #pragma unroll
  for (int ks = 0; ks < 2; ++ks) {
    short8 av = *(const short8*)(hb + l16 * 64 + ((ks * 32 + q * 8) ^ ((l16 & 7) << 3)));
    aA = __builtin_amdgcn_mfma_f32_16x16x32_bf16(av, wOv[ks * 64 + lane], aA, 0, 0, 0);
  }
  #pragma unroll
  for (int r = 0; r < 4; ++r) {
    size_t m = rowbase + (size_t)(4 * q + r);
    out_act[m * 16 + l16] = tanh_(aA[r]);
  }
}

extern "C" void kernel_launch(void* const* d_in, const int* in_sizes, int n_in,
                              void* d_out, int out_size, void* d_ws, size_t ws_size,
                              hipStream_t stream) {
  const float* obs  = (const float*)d_in[0];
  const float* h0   = (const float*)d_in[1];
  const float* c0   = (const float*)d_in[2];
  const float* W_in = (const float*)d_in[3];
  const float* b_in = (const float*)d_in[4];
  const float* W_ih = (const float*)d_in[5];
  const float* W_hh = (const float*)d_in[6];
  const float* b_ih = (const float*)d_in[7];
  const float* b_hh = (const float*)d_in[8];
  const float* W_out = (const float*)d_in[9];
  const float* b_out = (const float*)d_in[10];

  unsigned short* wsW = (unsigned short*)d_ws;
  float* ws_beff = (float*)((char*)d_ws + 67584);

  prep_kernel<<<133, 256, 0, stream>>>(W_in, b_in, W_ih, W_hh, b_ih, b_hh, W_out, wsW, ws_beff);
  lstm_main<<<BT / TILE, BLOCK, 0, stream>>>(obs, h0, c0, b_out, wsW, ws_beff, (float*)d_out);
}

// Round 6
// 95.788 us; speedup vs baseline: 2.0584x; 1.1949x over previous
//
#include <hip/hip_runtime.h>
#include <hip/hip_bf16.h>

#define BT 262144
#define BLOCK 256
#define NBLOCKS 512
#define NIT 8              // BT / (NBLOCKS * 64 rows per block-tile)

typedef __attribute__((ext_vector_type(8))) short short8;
typedef __attribute__((ext_vector_type(4))) float f32x4;
typedef __attribute__((ext_vector_type(4))) unsigned short u16x4;

__device__ __forceinline__ unsigned short f2bf(float f) {
  union { __hip_bfloat16 b; unsigned short u; } v;
  v.b = __float2bfloat16(f);
  return v.u;
}
__device__ __forceinline__ float frcp(float x) { return __builtin_amdgcn_rcpf(x); }
__device__ __forceinline__ float sigm(float x) { return frcp(1.0f + __expf(-x)); }
__device__ __forceinline__ float tanh_(float x) {
  float e = __expf(-2.0f * x);
  return (1.0f - e) * frcp(1.0f + e);
}

// Prep: W_eff = W_ih @ W_in, b_eff = b_ih + b_hh + W_ih @ b_in.
// COLUMN-PERMUTED gate fragments (same as R5): tile a maps fragment col
// l16 -> actual gate col 4*l16 + (a&3), so each lane owns 4 consecutive
// output columns after the D-layout -> dwordx4 c0 loads and c/h stores.
//   wE  ids [0,16384):      id = ((ks*16 + a)*64 + l)*8 + j
//       n = (a>>2)*64 + 4*(l&15) + (a&3), k = ks*32 + (l>>4)*8 + j
//   wH  ids [16384,32768):  same mapping, value = W_hh[n][k]
//   wO  ids [32768,33792):  (ks*64 + l)*8 + j, n = l&15, k = ks*32+(l>>4)*8+j
//   b_eff ids [33792,34048): floats at byte offset 67584
__global__ void prep_kernel(const float* __restrict__ W_in, const float* __restrict__ b_in,
                            const float* __restrict__ W_ih, const float* __restrict__ W_hh,
                            const float* __restrict__ b_ih, const float* __restrict__ b_hh,
                            const float* __restrict__ W_out,
                            unsigned short* __restrict__ wsW, float* __restrict__ ws_beff) {
  int id = blockIdx.x * blockDim.x + threadIdx.x;
  if (id < 16384) {                       // W_eff fragments
    int j = id & 7, l = (id >> 3) & 63, a = (id >> 9) & 15, ks = id >> 13;
    int n = (a >> 2) * 64 + 4 * (l & 15) + (a & 3);
    int k = ks * 32 + (l >> 4) * 8 + j;
    float s = 0.f;
    #pragma unroll 8
    for (int h = 0; h < 64; ++h) s = fmaf(W_ih[n * 64 + h], W_in[h * 64 + k], s);
    wsW[id] = f2bf(s);
  } else if (id < 32768) {                // W_hh fragments
    int e = id - 16384;
    int j = e & 7, l = (e >> 3) & 63, a = (e >> 9) & 15, ks = (e >> 13) & 1;
    int n = (a >> 2) * 64 + 4 * (l & 15) + (a & 3);
    int k = ks * 32 + (l >> 4) * 8 + j;
    wsW[id] = f2bf(W_hh[n * 64 + k]);
  } else if (id < 33792) {                // W_out fragments (unpermuted)
    int e = id - 32768;
    int j = e & 7, l = (e >> 3) & 63, ks = e >> 9;
    int n = l & 15;
    int k = ks * 32 + (l >> 4) * 8 + j;
    wsW[id] = f2bf(W_out[n * 64 + k]);
  } else if (id < 34048) {                // b_eff
    int n = id - 33792;
    float s = b_ih[n] + b_hh[n];
    #pragma unroll 8
    for (int h = 0; h < 64; ++h) s = fmaf(W_ih[n * 64 + h], b_in[h], s);
    ws_beff[n] = s;
  }
}

__device__ __forceinline__ short8 pack8(float4 lo, float4 hi) {
  short8 r;
  r[0] = (short)f2bf(lo.x); r[1] = (short)f2bf(lo.y);
  r[2] = (short)f2bf(lo.z); r[3] = (short)f2bf(lo.w);
  r[4] = (short)f2bf(hi.x); r[5] = (short)f2bf(hi.y);
  r[6] = (short)f2bf(hi.z); r[7] = (short)f2bf(hi.w);
  return r;
}

// Persistent blocks: stage weights ONCE, then barrier-free loop over 8 tiles
// with software-pipelined loads. 2 blocks/CU (76800 B LDS).
__global__ __launch_bounds__(BLOCK, 2) void lstm_main(
    const float* __restrict__ obs, const float* __restrict__ h0,
    const float* __restrict__ c0, const float* __restrict__ b_out,
    const unsigned short* __restrict__ wsW, const float* __restrict__ ws_beff,
    float* __restrict__ out) {
  __shared__ __attribute__((aligned(16))) unsigned char sbuf[68608];
  __shared__ __attribute__((aligned(16))) unsigned short hbuf[4][1024];
  unsigned short* sw = (unsigned short*)sbuf;

  const int tid = threadIdx.x;
  const int wv = tid >> 6;
  const int lane = tid & 63;
  const int l16 = lane & 15;
  const int q = lane >> 4;                 // 0..3

  // ---- stage full weight image -> LDS once (4288 uint4) ----
  for (int i = tid; i < 4288; i += BLOCK)
    ((uint4*)sbuf)[i] = ((const uint4*)wsW)[i];
  __syncthreads();

  // hoist biases to registers
  const float* beff_s = (const float*)(sbuf + 67584);
  float bias[16];
  #pragma unroll
  for (int a = 0; a < 16; ++a) bias[a] = beff_s[(a >> 2) * 64 + 4 * l16 + (a & 3)];
  const float boA = b_out[l16];

  const short8* wEv = (const short8*)sw;              // [2][16][64]
  const short8* wHv = (const short8*)(sw + 16384);    // [2][16][64]
  const short8* wOv = (const short8*)(sw + 32768);    // [2][64]
  unsigned short* hb = &hbuf[wv][0];

  float* out_act = out;
  float* out_h = out + (size_t)BT * 16;
  float* out_c = out + (size_t)BT * 80;

  float4 ro[2][4], rh[2][4];

  auto tile_rowbase = [&](int it) -> size_t {
    return ((size_t)(it * NBLOCKS + blockIdx.x)) * 64 + (size_t)wv * 16;
  };
  auto load_oh = [&](int it, int buf) {
    size_t rowbase = tile_rowbase(it);
    const float* po = obs + (rowbase + l16) * 64 + q * 8;
    const float* ph = h0 + (rowbase + l16) * 64 + q * 8;
    ro[buf][0] = *(const float4*)(po);
    ro[buf][1] = *(const float4*)(po + 4);
    ro[buf][2] = *(const float4*)(po + 32);
    ro[buf][3] = *(const float4*)(po + 36);
    rh[buf][0] = *(const float4*)(ph);
    rh[buf][1] = *(const float4*)(ph + 4);
    rh[buf][2] = *(const float4*)(ph + 32);
    rh[buf][3] = *(const float4*)(ph + 36);
  };

  load_oh(0, 0);
  #pragma unroll
  for (int it = 0; it < NIT; ++it) {
    const int cur = it & 1;
    const size_t rowbase = tile_rowbase(it);

    // c0 for current tile: issued now, consumed after the MFMA phase
    f32x4 cold[4];
    #pragma unroll
    for (int r = 0; r < 4; ++r)
      cold[r] = *(const f32x4*)(c0 + (rowbase + (size_t)(4 * q + r)) * 64 + 4 * l16);

    // prefetch next tile's obs/h0 (hidden under this tile's MFMAs)
    if (it + 1 < NIT) load_oh(it + 1, cur ^ 1);

    short8 aObs[2], aH[2];
    aObs[0] = pack8(ro[cur][0], ro[cur][1]);
    aObs[1] = pack8(ro[cur][2], ro[cur][3]);
    aH[0]   = pack8(rh[cur][0], rh[cur][1]);
    aH[1]   = pack8(rh[cur][2], rh[cur][3]);

    f32x4 acc[16];
    #pragma unroll
    for (int a = 0; a < 16; ++a)
      acc[a] = (f32x4){bias[a], bias[a], bias[a], bias[a]};

    #pragma unroll
    for (int ks = 0; ks < 2; ++ks) {
      #pragma unroll
      for (int a = 0; a < 16; ++a) {
        acc[a] = __builtin_amdgcn_mfma_f32_16x16x32_bf16(aObs[ks], wEv[(ks * 16 + a) * 64 + lane], acc[a], 0, 0, 0);
        acc[a] = __builtin_amdgcn_mfma_f32_16x16x32_bf16(aH[ks],  wHv[(ks * 16 + a) * 64 + lane], acc[a], 0, 0, 0);
      }
    }

    // elementwise; D layout: lane holds row 4q+r, cols 4*l16 + t
    #pragma unroll
    for (int r = 0; r < 4; ++r) {
      f32x4 c4, h4;
      u16x4 hb4;
      #pragma unroll
      for (int t = 0; t < 4; ++t) {
        float iv = sigm(acc[t][r]);
        float fv = sigm(acc[4 + t][r]);
        float gv = tanh_(acc[8 + t][r]);
        float ov = sigm(acc[12 + t][r]);
        float cnew = fmaf(fv, cold[r][t], iv * gv);
        float hnew = ov * tanh_(cnew);
        c4[t] = cnew;
        h4[t] = hnew;
        hb4[t] = f2bf(hnew);
      }
      const int hrow = 4 * q + r;
      const size_t m = rowbase + (size_t)hrow;
      *(f32x4*)(out_c + m * 64 + 4 * l16) = c4;
      *(f32x4*)(out_h + m * 64 + 4 * l16) = h4;
      *(u16x4*)(hb + hrow * 64 + ((4 * l16) ^ ((hrow & 7) << 3))) = hb4;
    }
    // hb is per-wave: same-wave ds_write -> ds_read ordering via lgkmcnt

    // action = tanh(h_new @ W_out^T + b_out); [-1,1] range => identity map
    f32x4 aA = (f32x4){boA, boA, boA, boA};
    #pragma unroll
    for (int ks = 0; ks < 2; ++ks) {
      short8 av = *(const short8*)(hb + l16 * 64 + ((ks * 32 + q * 8) ^ ((l16 & 7) << 3)));
      aA = __builtin_amdgcn_mfma_f32_16x16x32_bf16(av, wOv[ks * 64 + lane], aA, 0, 0, 0);
    }
    #pragma unroll
    for (int r = 0; r < 4; ++r) {
      size_t m = rowbase + (size_t)(4 * q + r);
      out_act[m * 16 + l16] = tanh_(aA[r]);
    }
  }
}

extern "C" void kernel_launch(void* const* d_in, const int* in_sizes, int n_in,
                              void* d_out, int out_size, void* d_ws, size_t ws_size,
                              hipStream_t stream) {
  const float* obs  = (const float*)d_in[0];
  const float* h0   = (const float*)d_in[1];
  const float* c0   = (const float*)d_in[2];
  const float* W_in = (const float*)d_in[3];
  const float* b_in = (const float*)d_in[4];
  const float* W_ih = (const float*)d_in[5];
  const float* W_hh = (const float*)d_in[6];
  const float* b_ih = (const float*)d_in[7];
  const float* b_hh = (const float*)d_in[8];
  const float* W_out = (const float*)d_in[9];
  const float* b_out = (const float*)d_in[10];

  unsigned short* wsW = (unsigned short*)d_ws;
  float* ws_beff = (float*)((char*)d_ws + 67584);

  prep_kernel<<<133, 256, 0, stream>>>(W_in, b_in, W_ih, W_hh, b_ih, b_hh, W_out, wsW, ws_beff);
  lstm_main<<<NBLOCKS, BLOCK, 0, stream>>>(obs, h0, c0, b_out, wsW, ws_beff, (float*)d_out);
}